// Round 16
// baseline (391.893 us; speedup 1.0000x reference)
//
#include <hip/hip_runtime.h>
#include <math.h>

#define TLEN 1024
#define BSZ  16
#define DIN  128
#define KP   16
#define NEIG 64
#define MOUT 128
#define CHUNK_T 256
#define NCHUNK  4

typedef float v2f __attribute__((ext_vector_type(2)));

// ws layout (float units)
static constexpr size_t XCQ_OFF = 0;        // 262144: xc f32 [t][b][k]
static constexpr size_t LAM_OFF = 262144;   // 2048:  lambda c32
static constexpr size_t BQ_OFF  = 264192;   // 2048:  B' c32
static constexpr size_t CP_OFF  = 266240;   // 262144: Cp c32 [(k*64+j)*128+m]
static constexpr size_t ST_OFF  = 528384;   // 65536: scan state
static constexpr size_t S2_OFF  = 593920;   // 8388608: s2 chunk [4096][1024] float2
static constexpr size_t P_OFF   = 8982528;  // 8388608: k-split partials [16][4096][128]
// total: 17,371,136 floats = 69.48 MB (proven usable)

__device__ __forceinline__ float f32cos(float x) { return (float)cos((double)x); }
__device__ __forceinline__ float f32sin(float x) { return (float)sin((double)x); }

__device__ __forceinline__ float2 cdiv32(float ar, float ai, float cr, float ci) {
  float2 o;
  if (fabsf(ci) <= fabsf(cr)) {
    float rat = __fdiv_rn(ci, cr);
    float scl = __fdiv_rn(1.0f, __fadd_rn(cr, __fmul_rn(ci, rat)));
    o.x = __fmul_rn(__fadd_rn(ar, __fmul_rn(ai, rat)), scl);
    o.y = __fmul_rn(__fsub_rn(ai, __fmul_rn(ar, rat)), scl);
  } else {
    float rat = __fdiv_rn(cr, ci);
    float scl = __fdiv_rn(1.0f, __fadd_rn(ci, __fmul_rn(cr, rat)));
    o.x = __fmul_rn(__fadd_rn(__fmul_rn(ar, rat), ai), scl);
    o.y = __fmul_rn(__fsub_rn(__fmul_rn(ai, rat), ar), scl);
  }
  return o;
}

// ---------------------------------------------------------------------------
__global__ __launch_bounds__(256) void k_lam_B(const float* __restrict__ theta,
                        float2* __restrict__ lam, float2* __restrict__ Bq) {
  __shared__ float2 terms[4][64];
  int wid  = threadIdx.x >> 6;
  int lane = threadIdx.x & 63;
  int idx = blockIdx.x * 4 + wid;
  int k = idx >> 6, j = idx & 63;
  float thj = (j < 32) ? theta[k * 32 + j] : -theta[k * 32 + (j - 32)];
  float ljr = f32cos(thj), lji = f32sin(thj);
  float2 tm = make_float2(0.f, 0.f);
  if (lane != j) {
    int i = lane;
    float thi = (i < 32) ? theta[k * 32 + i] : -theta[k * 32 + (i - 32)];
    float lir = f32cos(thi), lii = f32sin(thi);
    float2 r = cdiv32(lir, lii, ljr, lji);
    float tr = __fsub_rn(1.0f, r.x);
    float ti = __fsub_rn(0.0f, r.y);
    double h = sqrt((double)tr * tr + (double)ti * ti);
    tm.x = (float)log(h);
    tm.y = (float)atan2((double)ti, (double)tr);
  }
  terms[wid][lane] = tm;
  __syncthreads();
  if (lane == 0) {
    lam[idx] = make_float2(ljr, lji);
    float sr = 0.f, si = 0.f;
    for (int i = 0; i < NEIG; ++i) {
      sr = __fadd_rn(sr, terms[wid][i].x);
      si = __fadd_rn(si, terms[wid][i].y);
    }
    float er = (float)exp((double)(-sr));
    float cc = f32cos(-si), ss = f32sin(-si);
    Bq[idx] = make_float2(__fmul_rn(er, cc), __fmul_rn(er, ss));
  }
}

// ---------------------------------------------------------------------------
__global__ __launch_bounds__(128) void k_Cp(const float* __restrict__ theta,
                     const float* __restrict__ C, float2* __restrict__ Cp) {
  __shared__ float2 sU[64];
  __shared__ float  sC[128][65];
  int tid = threadIdx.x;
  int kj = blockIdx.x;
  int j = kj & 63, k = kj >> 6;
  float lnim = (j < 32) ? theta[k * 32 + j] : -theta[k * 32 + (j - 32)];
  if (tid < 64) {
    int i = tid;
    float p = (float)(63 - i);
    float ph = -__fmul_rn(p, lnim);
    sU[i] = make_float2(f32cos(ph), f32sin(ph));
  }
  const float* Ck = C + ((size_t)k << 13);
  for (int e = tid; e < 128 * 64; e += 128) {
    sC[e >> 6][e & 63] = Ck[e];
  }
  __syncthreads();
  int m = tid;
  float ar = 0.f, ai = 0.f;
  #pragma unroll 8
  for (int i = 0; i < NEIG; ++i) {
    float Cv = sC[m][i];
    float2 U = sU[i];
    ar = __fadd_rn(ar, __fmul_rn(Cv, U.x));
    ai = __fadd_rn(ai, __fmul_rn(Cv, U.y));
  }
  Cp[(size_t)(k * 64 + j) * MOUT + m] = make_float2(ar, ai);
}

// ---------------------------------------------------------------------------
__global__ __launch_bounds__(256) void k_xc(const float* __restrict__ x,
                     const float* __restrict__ R, float* __restrict__ xcq) {
  __shared__ float sX[16][132];
  __shared__ float sR[128][16];
  int tid = threadIdx.x;
  int rBase = blockIdx.x * 16;
  for (int e = tid; e < DIN * KP; e += 256) sR[e >> 4][e & 15] = R[e];
  #pragma unroll
  for (int it = 0; it < 2; ++it) {
    int e = tid + it * 256;
    int row = e >> 5, q = e & 31;
    int g = rBase + row;
    int t = g >> 4, b = g & 15;
    float4 v = *(const float4*)(x + ((size_t)b * TLEN + t) * DIN + q * 4);
    *(float4*)&sX[row][q * 4] = v;
  }
  __syncthreads();
  int r = tid >> 4, k = tid & 15;
  double acc = 0.0;
  #pragma unroll 16
  for (int d = 0; d < DIN; ++d)
    acc = fma((double)sX[r][d], (double)sR[d][k], acc);
  xcq[(size_t)(rBase + r) * KP + k] = (float)acc;
}

// ---------------------------------------------------------------------------
// Scan v6 (round 12, proven): single pass, 1 mode/lane, register alpha
// pipeline in batches of 8. Bit-identical per-step op sequence.
__global__ __launch_bounds__(64) void k_scan(const float2* __restrict__ lam,
                        const float2* __restrict__ Bq,
                        const float* __restrict__ xcq,
                        float2* __restrict__ S2,
                        float* __restrict__ state, int c) {
  __shared__ float sXq[CHUNK_T];
  int j = threadIdx.x;
  int chain = blockIdx.x;              // b*16 + k
  int b = chain >> 4, k = chain & 15;
  int mode = k * 64 + j;
  int t0 = c * CHUNK_T;
  int tlBeg = (c == 0) ? 1 : 0;
  for (int i = j; i < CHUNK_T; i += 64) {
    int g = t0 + tlBeg - 1 + i;
    sXq[i] = xcq[(size_t)g * (BSZ * KP) + b * KP + k];
  }
  __syncthreads();
  float lr = lam[mode].x, li = lam[mode].y;
  float Br = Bq[mode].x,  Bi = Bq[mode].y;
  float* st = state + (size_t)(chain * 64 + j) * 4;
  float s1r, s1i, s2r, s2i;
  if (c == 0) { s1r = s1i = s2r = s2i = 0.f; }
  else        { s1r = st[0]; s1i = st[1]; s2r = st[2]; s2i = st[3]; }
  if (c == 0)
    S2[(size_t)(0 * BSZ + b) * 1024 + mode] = make_float2(s2r, s2i);

  int tl = tlBeg;
  for (; tl + 8 <= CHUNK_T; tl += 8) {
    float als[8];
    #pragma unroll
    for (int u = 0; u < 8; ++u) {
      float xq = sXq[tl - tlBeg + u];
      float lsr = __fsub_rn(__fmul_rn(lr, s1r), __fmul_rn(li, s1i));
      float lsi = __fadd_rn(__fmul_rn(lr, s1i), __fmul_rn(li, s1r));
      float h  = (float)sqrt((double)lsr * lsr + (double)lsi * lsi);
      als[u] = __fdiv_rn(1.0f, __fsqrt_rn(__fadd_rn(1.0f, __fmul_rn(h, h))));
      float bxr = __fmul_rn(xq, Br), bxi = __fmul_rn(xq, Bi);
      s1r = __fadd_rn(lsr, bxr);
      s1i = __fadd_rn(lsi, bxi);
    }
    #pragma unroll
    for (int u = 0; u < 8; ++u) {
      float xq = sXq[tl - tlBeg + u];
      float al = als[u];
      float bxr = __fmul_rn(xq, Br), bxi = __fmul_rn(xq, Bi);
      float a2r = __fmul_rn(al, lr), a2i = __fmul_rn(al, li);
      float t2r = __fsub_rn(__fmul_rn(a2r, s2r), __fmul_rn(a2i, s2i));
      float t2i = __fadd_rn(__fmul_rn(a2r, s2i), __fmul_rn(a2i, s2r));
      s2r = __fadd_rn(t2r, bxr);
      s2i = __fadd_rn(t2i, bxi);
      S2[(size_t)((tl + u) * BSZ + b) * 1024 + mode] = make_float2(s2r, s2i);
    }
  }
  for (; tl < CHUNK_T; ++tl) {
    float xq = sXq[tl - tlBeg];
    float lsr = __fsub_rn(__fmul_rn(lr, s1r), __fmul_rn(li, s1i));
    float lsi = __fadd_rn(__fmul_rn(lr, s1i), __fmul_rn(li, s1r));
    float h  = (float)sqrt((double)lsr * lsr + (double)lsi * lsi);
    float al = __fdiv_rn(1.0f, __fsqrt_rn(__fadd_rn(1.0f, __fmul_rn(h, h))));
    float bxr = __fmul_rn(xq, Br), bxi = __fmul_rn(xq, Bi);
    float a2r = __fmul_rn(al, lr), a2i = __fmul_rn(al, li);
    float t2r = __fsub_rn(__fmul_rn(a2r, s2r), __fmul_rn(a2i, s2i));
    float t2i = __fadd_rn(__fmul_rn(a2r, s2i), __fmul_rn(a2i, s2r));
    s2r = __fadd_rn(t2r, bxr);
    s2i = __fadd_rn(t2i, bxi);
    s1r = __fadd_rn(lsr, bxr);
    s1i = __fadd_rn(lsi, bxi);
    S2[(size_t)(tl * BSZ + b) * 1024 + mode] = make_float2(s2r, s2i);
  }
  st[0] = s1r; st[1] = s1i; st[2] = s2r; st[3] = s2i;
}

// ---------------------------------------------------------------------------
// k_y v13: R15 geometry (split-k x16 x 64 row-tiles, BM=64, 256 thr, 4x8
// microtile, 4 n-phases, 4 blocks/CU) + packed-f32 inner loop via inline asm.
// Cp staged SoA in LDS: Re plane and NEGATED-Im plane (negation exact), so
// term = fadd(pk_mul(re,cx), pk_mul(im,ncy)) == fsub(re*cx, im*cy) bitwise,
// per-slot IEEE RN. op_sel broadcasts the a.re/a.im halves (no splat movs).
__global__ __launch_bounds__(256) void k_y(const float2* __restrict__ S2,
                     const float2* __restrict__ Cp, const float* __restrict__ xcq,
                     const float* __restrict__ D, const float* __restrict__ Dov,
                     float* __restrict__ P, int c) {
  __shared__ float2 sS2t[16][65];    // 8.3 KB  [n][row] (re,im)
  __shared__ float  sCpRe[16][130];  // 8.3 KB  [n][col] re
  __shared__ float  sCpIm[16][130];  // 8.3 KB  [n][col] -im
  int tid = threadIdx.x;
  int kidx = blockIdx.x >> 6;        // 0..15
  int rt   = blockIdx.x & 63;        // 0..63
  int rowBase = rt * 64;             // chunk-local
  int rg = tid & 15;                 // rows rg + 16j (j=0..3)
  int cg = tid >> 4;                 // cols cg*8 .. +7
  int c0 = cg * 8;
  v2f acc2[4][4];                    // [row][colpair] -> cols (c0+2q, c0+2q+1)
  #pragma unroll
  for (int jj = 0; jj < 4; ++jj)
    #pragma unroll
    for (int q = 0; q < 4; ++q) acc2[jj][q] = (v2f)(0.f);

  #pragma unroll 1
  for (int nh = 0; nh < 4; ++nh) {
    __syncthreads();
    // stage sS2t [16 n][64 row]: 512 float4, 2/thread
    #pragma unroll
    for (int it = 0; it < 2; ++it) {
      int e = tid + it * 256;          // 0..511
      int n2 = (e & 7) * 2;
      int row = e >> 3;                // 0..63
      float4 v = *(const float4*)(S2 + (size_t)(rowBase + row) * 1024
                                     + kidx * 64 + nh * 16 + n2);
      sS2t[n2][row]     = make_float2(v.x, v.y);
      sS2t[n2 + 1][row] = make_float2(v.z, v.w);
    }
    // stage Cp SoA: 1024 float4, 4/thread; Im plane stored negated (exact)
    #pragma unroll
    for (int it = 0; it < 4; ++it) {
      int e = tid + it * 256;
      int col2 = (e & 63) * 2;
      int n = e >> 6;                  // 0..15
      float4 v = *(const float4*)(Cp + (size_t)(kidx * 64 + nh * 16 + n) * MOUT + col2);
      sCpRe[n][col2]     = v.x;
      sCpRe[n][col2 + 1] = v.z;
      sCpIm[n][col2]     = -v.y;
      sCpIm[n][col2 + 1] = -v.w;
    }
    __syncthreads();
    #pragma unroll 2
    for (int n = 0; n < 16; ++n) {
      v2f a2[4];
      #pragma unroll
      for (int jj = 0; jj < 4; ++jj)
        a2[jj] = *(const v2f*)&sS2t[n][rg + jj * 16];   // {re, im}
      v2f wx[4], wy[4];
      #pragma unroll
      for (int q = 0; q < 4; ++q) {
        wx[q] = *(const v2f*)&sCpRe[n][c0 + q * 2];     // {cx0, cx1}
        wy[q] = *(const v2f*)&sCpIm[n][c0 + q * 2];     // {-cy0, -cy1}
      }
      #pragma unroll
      for (int jj = 0; jj < 4; ++jj) {
        #pragma unroll
        for (int q = 0; q < 4; ++q) {
          v2f t0, t1, t2;
          // t0 = {re*cx0, re*cx1}
          asm("v_pk_mul_f32 %0, %1, %2 op_sel:[0,0] op_sel_hi:[0,1]"
              : "=v"(t0) : "v"(a2[jj]), "v"(wx[q]));
          // t1 = {im*(-cy0), im*(-cy1)}
          asm("v_pk_mul_f32 %0, %1, %2 op_sel:[1,0] op_sel_hi:[1,1]"
              : "=v"(t1) : "v"(a2[jj]), "v"(wy[q]));
          // term = t0 + t1  (== fsub(re*cx, im*cy) bitwise)
          asm("v_pk_add_f32 %0, %1, %2 op_sel:[0,0] op_sel_hi:[1,1]"
              : "=v"(t2) : "v"(t0), "v"(t1));
          // acc += term
          asm("v_pk_add_f32 %0, %1, %2 op_sel:[0,0] op_sel_hi:[1,1]"
              : "=v"(acc2[jj][q]) : "v"(acc2[jj][q]), "v"(t2));
        }
      }
    }
  }
  // epilogue: P[kidx][row][col] = (accn + xc*D) + Do  (scalar, order as R4-15)
  float dv[8], ovv[8];
  *(float4*)&dv[0]  = *(const float4*)(D + kidx * MOUT + c0);
  *(float4*)&dv[4]  = *(const float4*)(D + kidx * MOUT + c0 + 4);
  *(float4*)&ovv[0] = *(const float4*)(Dov + c0);
  *(float4*)&ovv[4] = *(const float4*)(Dov + c0 + 4);
  #pragma unroll
  for (int jj = 0; jj < 4; ++jj) {
    int row = rowBase + rg + jj * 16;
    float xv = xcq[(size_t)(c * 4096 + row) * KP + kidx];
    float res[8];
    #pragma unroll
    for (int q = 0; q < 8; ++q) {
      float accv = (q & 1) ? acc2[jj][q >> 1].y : acc2[jj][q >> 1].x;
      res[q] = __fadd_rn(__fadd_rn(accv, __fmul_rn(xv, dv[q])), ovv[q]);
    }
    float* pp = P + ((size_t)kidx * 4096 + row) * MOUT + c0;
    *(float4*)pp       = make_float4(res[0], res[1], res[2], res[3]);
    *(float4*)(pp + 4) = make_float4(res[4], res[5], res[6], res[7]);
  }
}

// ---------------------------------------------------------------------------
// out = (P0 + ... + P15)/16, k ascending (bit-matches rounds 4-6 msum).
__global__ __launch_bounds__(256) void k_combine(const float* __restrict__ P,
                     float* __restrict__ out, int c) {
  int idx = blockIdx.x * 256 + threadIdx.x;   // 131072 float4s
  int r  = idx >> 5;
  int m4 = (idx & 31) * 4;
  float4 s = *(const float4*)(P + (size_t)r * MOUT + m4);
  #pragma unroll
  for (int k = 1; k < KP; ++k) {
    float4 p = *(const float4*)(P + ((size_t)k * 4096 + r) * MOUT + m4);
    s.x = __fadd_rn(s.x, p.x);
    s.y = __fadd_rn(s.y, p.y);
    s.z = __fadd_rn(s.z, p.z);
    s.w = __fadd_rn(s.w, p.w);
  }
  int rg = c * 4096 + r;
  int t = rg >> 4, b = rg & 15;
  float4 res;
  res.x = __fdiv_rn(s.x, 16.0f);
  res.y = __fdiv_rn(s.y, 16.0f);
  res.z = __fdiv_rn(s.z, 16.0f);
  res.w = __fdiv_rn(s.w, 16.0f);
  *(float4*)(out + ((size_t)b * TLEN + t) * MOUT + m4) = res;
}

// ---------------------------------------------------------------------------
extern "C" void kernel_launch(void* const* d_in, const int* in_sizes, int n_in,
                              void* d_out, int out_size, void* d_ws, size_t ws_size,
                              hipStream_t stream) {
  const float* x     = (const float*)d_in[0];
  const float* R     = (const float*)d_in[1];
  const float* theta = (const float*)d_in[2];
  const float* C     = (const float*)d_in[3];
  const float* D     = (const float*)d_in[4];
  const float* Do    = (const float*)d_in[5];
  float* out = (float*)d_out;
  float* ws  = (float*)d_ws;
  float*  xcq = ws + XCQ_OFF;
  float2* lam = (float2*)(ws + LAM_OFF);
  float2* Bq  = (float2*)(ws + BQ_OFF);
  float2* Cp  = (float2*)(ws + CP_OFF);
  float*  st  = ws + ST_OFF;
  float2* S2  = (float2*)(ws + S2_OFF);
  float*  P   = ws + P_OFF;

  hipLaunchKernelGGL(k_lam_B, dim3(256),  dim3(256), 0, stream, theta, lam, Bq);
  hipLaunchKernelGGL(k_Cp,    dim3(1024), dim3(128), 0, stream, theta, C, Cp);
  hipLaunchKernelGGL(k_xc,    dim3(1024), dim3(256), 0, stream, x, R, xcq);
  for (int c = 0; c < NCHUNK; ++c) {
    hipLaunchKernelGGL(k_scan,    dim3(256),  dim3(64),  0, stream, lam, Bq, xcq, S2, st, c);
    hipLaunchKernelGGL(k_y,       dim3(1024), dim3(256), 0, stream, S2, Cp, xcq, D, Do, P, c);
    hipLaunchKernelGGL(k_combine, dim3(512),  dim3(256), 0, stream, P, out, c);
  }
}

// Round 17
// 345.380 us; speedup vs baseline: 1.1347x; 1.1347x over previous
//
#include <hip/hip_runtime.h>
#include <math.h>

#define TLEN 1024
#define BSZ  16
#define DIN  128
#define KP   16
#define NEIG 64
#define MOUT 128
#define CHUNK_T 128
#define NCHUNK  8
#define CROWS   2048            // rows per chunk = CHUNK_T*BSZ

// ws layout (float units)
static constexpr size_t XCQ_OFF = 0;        // 262144: xc f32 [t][b][k]
static constexpr size_t LAM_OFF = 262144;   // 2048:  lambda c32
static constexpr size_t BQ_OFF  = 264192;   // 2048:  B' c32
static constexpr size_t CP_OFF  = 266240;   // 262144: Cp c32 [(k*64+j)*128+m]
static constexpr size_t ST_OFF  = 528384;   // 65536: scan state
static constexpr size_t S2_OFF  = 593920;   // 2 x 4194304: s2 double buffer [2048][1024] f2
static constexpr size_t P_OFF   = 8982528;  // 2 x 4194304: P double buffer [16][2048][128]
// total: 17,371,136 floats = 69.48 MB (proven usable)

__device__ __forceinline__ float f32cos(float x) { return (float)cos((double)x); }
__device__ __forceinline__ float f32sin(float x) { return (float)sin((double)x); }

__device__ __forceinline__ float2 cdiv32(float ar, float ai, float cr, float ci) {
  float2 o;
  if (fabsf(ci) <= fabsf(cr)) {
    float rat = __fdiv_rn(ci, cr);
    float scl = __fdiv_rn(1.0f, __fadd_rn(cr, __fmul_rn(ci, rat)));
    o.x = __fmul_rn(__fadd_rn(ar, __fmul_rn(ai, rat)), scl);
    o.y = __fmul_rn(__fsub_rn(ai, __fmul_rn(ar, rat)), scl);
  } else {
    float rat = __fdiv_rn(cr, ci);
    float scl = __fdiv_rn(1.0f, __fadd_rn(ci, __fmul_rn(cr, rat)));
    o.x = __fmul_rn(__fadd_rn(__fmul_rn(ar, rat), ai), scl);
    o.y = __fmul_rn(__fsub_rn(__fmul_rn(ai, rat), ar), scl);
  }
  return o;
}

// ---------------------------------------------------------------------------
__global__ __launch_bounds__(256) void k_lam_B(const float* __restrict__ theta,
                        float2* __restrict__ lam, float2* __restrict__ Bq) {
  __shared__ float2 terms[4][64];
  int wid  = threadIdx.x >> 6;
  int lane = threadIdx.x & 63;
  int idx = blockIdx.x * 4 + wid;
  int k = idx >> 6, j = idx & 63;
  float thj = (j < 32) ? theta[k * 32 + j] : -theta[k * 32 + (j - 32)];
  float ljr = f32cos(thj), lji = f32sin(thj);
  float2 tm = make_float2(0.f, 0.f);
  if (lane != j) {
    int i = lane;
    float thi = (i < 32) ? theta[k * 32 + i] : -theta[k * 32 + (i - 32)];
    float lir = f32cos(thi), lii = f32sin(thi);
    float2 r = cdiv32(lir, lii, ljr, lji);
    float tr = __fsub_rn(1.0f, r.x);
    float ti = __fsub_rn(0.0f, r.y);
    double h = sqrt((double)tr * tr + (double)ti * ti);
    tm.x = (float)log(h);
    tm.y = (float)atan2((double)ti, (double)tr);
  }
  terms[wid][lane] = tm;
  __syncthreads();
  if (lane == 0) {
    lam[idx] = make_float2(ljr, lji);
    float sr = 0.f, si = 0.f;
    for (int i = 0; i < NEIG; ++i) {
      sr = __fadd_rn(sr, terms[wid][i].x);
      si = __fadd_rn(si, terms[wid][i].y);
    }
    float er = (float)exp((double)(-sr));
    float cc = f32cos(-si), ss = f32sin(-si);
    Bq[idx] = make_float2(__fmul_rn(er, cc), __fmul_rn(er, ss));
  }
}

// ---------------------------------------------------------------------------
__global__ __launch_bounds__(128) void k_Cp(const float* __restrict__ theta,
                     const float* __restrict__ C, float2* __restrict__ Cp) {
  __shared__ float2 sU[64];
  __shared__ float  sC[128][65];
  int tid = threadIdx.x;
  int kj = blockIdx.x;
  int j = kj & 63, k = kj >> 6;
  float lnim = (j < 32) ? theta[k * 32 + j] : -theta[k * 32 + (j - 32)];
  if (tid < 64) {
    int i = tid;
    float p = (float)(63 - i);
    float ph = -__fmul_rn(p, lnim);
    sU[i] = make_float2(f32cos(ph), f32sin(ph));
  }
  const float* Ck = C + ((size_t)k << 13);
  for (int e = tid; e < 128 * 64; e += 128) {
    sC[e >> 6][e & 63] = Ck[e];
  }
  __syncthreads();
  int m = tid;
  float ar = 0.f, ai = 0.f;
  #pragma unroll 8
  for (int i = 0; i < NEIG; ++i) {
    float Cv = sC[m][i];
    float2 U = sU[i];
    ar = __fadd_rn(ar, __fmul_rn(Cv, U.x));
    ai = __fadd_rn(ai, __fmul_rn(Cv, U.y));
  }
  Cp[(size_t)(k * 64 + j) * MOUT + m] = make_float2(ar, ai);
}

// ---------------------------------------------------------------------------
__global__ __launch_bounds__(256) void k_xc(const float* __restrict__ x,
                     const float* __restrict__ R, float* __restrict__ xcq) {
  __shared__ float sX[16][132];
  __shared__ float sR[128][16];
  int tid = threadIdx.x;
  int rBase = blockIdx.x * 16;
  for (int e = tid; e < DIN * KP; e += 256) sR[e >> 4][e & 15] = R[e];
  #pragma unroll
  for (int it = 0; it < 2; ++it) {
    int e = tid + it * 256;
    int row = e >> 5, q = e & 31;
    int g = rBase + row;
    int t = g >> 4, b = g & 15;
    float4 v = *(const float4*)(x + ((size_t)b * TLEN + t) * DIN + q * 4);
    *(float4*)&sX[row][q * 4] = v;
  }
  __syncthreads();
  int r = tid >> 4, k = tid & 15;
  double acc = 0.0;
  #pragma unroll 16
  for (int d = 0; d < DIN; ++d)
    acc = fma((double)sX[r][d], (double)sR[d][k], acc);
  xcq[(size_t)(rBase + r) * KP + k] = (float)acc;
}

// ---------------------------------------------------------------------------
// Fused pipeline stage L (0..9): block roles
//   [0, nKy):             k_y for chunk cK = L-1   (1<=L<=8)
//   [nKy, nKy+nScan):     scan for chunk cS = L    (L<8)
//   [nKy+nScan, end):     combine for chunk cC = L-2 (L>=2)
// Roles are block-uniform; barrier counts differ per role but each block
// executes exactly one role. All per-element arithmetic identical to R15.
__global__ __launch_bounds__(256) void k_fused(int L,
                     const float2* __restrict__ lam, const float2* __restrict__ Bq,
                     const float* __restrict__ xcq, const float2* __restrict__ Cp,
                     const float* __restrict__ D, const float* __restrict__ Dov,
                     float2* __restrict__ S2all, float* __restrict__ Pall,
                     float* __restrict__ state, float* __restrict__ out) {
  __shared__ float2 sS2t[16][65];    // k_y: [n][row]  8.3 KB
  __shared__ float2 sCp[16][66];     // k_y: [n][col]  8.4 KB
  __shared__ float  sXq[4][132];     // scan: per-wave xq window 2.1 KB
  int bid = blockIdx.x;
  int tid = threadIdx.x;
  int nKy   = (L >= 1 && L <= 8) ? 1024 : 0;
  int nScan = (L < 8) ? 64 : 0;

  if (bid < nKy) {
    // ================= k_y role: chunk cK = L-1 =================
    int cK = L - 1;
    const float2* S2 = S2all + (size_t)(cK & 1) * 2097152;   // float2 units
    float* P = Pall + (size_t)(cK & 1) * 4194304;
    int kidx = bid >> 6;             // 0..15
    int rem  = bid & 63;
    int rowBase = (rem >> 1) * 64;   // 0..1984 (chunk-local)
    int colBase = (rem & 1) * 64;
    int rg = tid & 15;               // rows rg + 16j (j=0..3)
    int cg = tid >> 4;               // cols colBase + cg*4 .. +3
    float acc[4][4];
    #pragma unroll
    for (int jj = 0; jj < 4; ++jj)
      #pragma unroll
      for (int q = 0; q < 4; ++q) acc[jj][q] = 0.f;

    #pragma unroll 1
    for (int nh = 0; nh < 4; ++nh) {
      __syncthreads();
      // stage sS2t [16 n][64 row]: 512 float4, 2/thread
      #pragma unroll
      for (int it = 0; it < 2; ++it) {
        int e = tid + it * 256;        // 0..511
        int n2 = (e & 7) * 2;
        int row = e >> 3;              // 0..63
        float4 v = *(const float4*)(S2 + (size_t)(rowBase + row) * 1024
                                       + kidx * 64 + nh * 16 + n2);
        sS2t[n2][row]     = make_float2(v.x, v.y);
        sS2t[n2 + 1][row] = make_float2(v.z, v.w);
      }
      // stage sCp [16 n][64 col]: 512 float4, 2/thread
      #pragma unroll
      for (int it = 0; it < 2; ++it) {
        int e = tid + it * 256;
        int col2 = (e & 31) * 2;       // 0..62
        int n = e >> 5;                // 0..15
        float4 v = *(const float4*)(Cp + (size_t)(kidx * 64 + nh * 16 + n) * MOUT
                                       + colBase + col2);
        *(float4*)&sCp[n][col2] = v;
      }
      __syncthreads();
      #pragma unroll 4
      for (int n = 0; n < 16; ++n) {
        float2 a[4];
        #pragma unroll
        for (int jj = 0; jj < 4; ++jj) a[jj] = sS2t[n][rg + jj * 16];
        float4 w0 = *(const float4*)&sCp[n][cg * 4];
        float4 w1 = *(const float4*)&sCp[n][cg * 4 + 2];
        float cx[4] = {w0.x, w0.z, w1.x, w1.z};
        float cy[4] = {w0.y, w0.w, w1.y, w1.w};
        #pragma unroll
        for (int jj = 0; jj < 4; ++jj)
          #pragma unroll
          for (int q = 0; q < 4; ++q)
            acc[jj][q] = __fadd_rn(acc[jj][q],
                __fsub_rn(__fmul_rn(a[jj].x, cx[q]), __fmul_rn(a[jj].y, cy[q])));
      }
    }
    // epilogue: P[kidx][row][col] = (accn + xc*D) + Do
    float4 d4 = *(const float4*)(D + kidx * MOUT + colBase + cg * 4);
    float4 o4 = *(const float4*)(Dov + colBase + cg * 4);
    float dv[4] = {d4.x, d4.y, d4.z, d4.w};
    float ov[4] = {o4.x, o4.y, o4.z, o4.w};
    #pragma unroll
    for (int jj = 0; jj < 4; ++jj) {
      int row = rowBase + rg + jj * 16;
      float xv = xcq[(size_t)(cK * CROWS + row) * KP + kidx];
      float res[4];
      #pragma unroll
      for (int q = 0; q < 4; ++q)
        res[q] = __fadd_rn(__fadd_rn(acc[jj][q], __fmul_rn(xv, dv[q])), ov[q]);
      *(float4*)(P + ((size_t)kidx * CROWS + row) * MOUT + colBase + cg * 4)
          = make_float4(res[0], res[1], res[2], res[3]);
    }
  } else if (bid < nKy + nScan) {
    // ================= scan role: chunk cS = L =================
    int cS = L;
    float2* S2 = S2all + (size_t)(cS & 1) * 2097152;
    int w = tid >> 6, j = tid & 63;
    int chain = (bid - nKy) * 4 + w;   // 0..255 = b*16+k
    int b = chain >> 4;
    int mode = (chain & 15) * 64 + j;
    int t0 = cS * CHUNK_T;
    int tlBeg = (cS == 0) ? 1 : 0;
    for (int i = j; i < CHUNK_T; i += 64) {
      int g = t0 + tlBeg - 1 + i;
      sXq[w][i] = xcq[(size_t)g * 256 + chain];
    }
    __syncthreads();
    float lr = lam[mode + (chain & 15) * 0].x, li = lam[mode].y;  // mode already k*64+j
    lr = lam[mode].x;
    float Br = Bq[mode].x, Bi = Bq[mode].y;
    float* st = state + (size_t)(chain * 64 + j) * 4;
    float s1r, s1i, s2r, s2i;
    if (cS == 0) { s1r = s1i = s2r = s2i = 0.f; }
    else         { s1r = st[0]; s1i = st[1]; s2r = st[2]; s2i = st[3]; }
    if (cS == 0)
      S2[(size_t)(0 * BSZ + b) * 1024 + mode] = make_float2(s2r, s2i);

    int tl = tlBeg;
    for (; tl + 8 <= CHUNK_T; tl += 8) {
      float als[8];
      #pragma unroll
      for (int u = 0; u < 8; ++u) {
        float xq = sXq[w][tl - tlBeg + u];
        float lsr = __fsub_rn(__fmul_rn(lr, s1r), __fmul_rn(li, s1i));
        float lsi = __fadd_rn(__fmul_rn(lr, s1i), __fmul_rn(li, s1r));
        float h  = (float)sqrt((double)lsr * lsr + (double)lsi * lsi);
        als[u] = __fdiv_rn(1.0f, __fsqrt_rn(__fadd_rn(1.0f, __fmul_rn(h, h))));
        float bxr = __fmul_rn(xq, Br), bxi = __fmul_rn(xq, Bi);
        s1r = __fadd_rn(lsr, bxr);
        s1i = __fadd_rn(lsi, bxi);
      }
      #pragma unroll
      for (int u = 0; u < 8; ++u) {
        float xq = sXq[w][tl - tlBeg + u];
        float al = als[u];
        float bxr = __fmul_rn(xq, Br), bxi = __fmul_rn(xq, Bi);
        float a2r = __fmul_rn(al, lr), a2i = __fmul_rn(al, li);
        float t2r = __fsub_rn(__fmul_rn(a2r, s2r), __fmul_rn(a2i, s2i));
        float t2i = __fadd_rn(__fmul_rn(a2r, s2i), __fmul_rn(a2i, s2r));
        s2r = __fadd_rn(t2r, bxr);
        s2i = __fadd_rn(t2i, bxi);
        S2[(size_t)((tl + u) * BSZ + b) * 1024 + mode] = make_float2(s2r, s2i);
      }
    }
    for (; tl < CHUNK_T; ++tl) {
      float xq = sXq[w][tl - tlBeg];
      float lsr = __fsub_rn(__fmul_rn(lr, s1r), __fmul_rn(li, s1i));
      float lsi = __fadd_rn(__fmul_rn(lr, s1i), __fmul_rn(li, s1r));
      float h  = (float)sqrt((double)lsr * lsr + (double)lsi * lsi);
      float al = __fdiv_rn(1.0f, __fsqrt_rn(__fadd_rn(1.0f, __fmul_rn(h, h))));
      float bxr = __fmul_rn(xq, Br), bxi = __fmul_rn(xq, Bi);
      float a2r = __fmul_rn(al, lr), a2i = __fmul_rn(al, li);
      float t2r = __fsub_rn(__fmul_rn(a2r, s2r), __fmul_rn(a2i, s2i));
      float t2i = __fadd_rn(__fmul_rn(a2r, s2i), __fmul_rn(a2i, s2r));
      s2r = __fadd_rn(t2r, bxr);
      s2i = __fadd_rn(t2i, bxi);
      s1r = __fadd_rn(lsr, bxr);
      s1i = __fadd_rn(lsi, bxi);
      S2[(size_t)(tl * BSZ + b) * 1024 + mode] = make_float2(s2r, s2i);
    }
    st[0] = s1r; st[1] = s1i; st[2] = s2r; st[3] = s2i;
  } else {
    // ================= combine role: chunk cC = L-2 =================
    int cC = L - 2;
    const float* P = Pall + (size_t)(cC & 1) * 4194304;
    int cb = bid - nKy - nScan;        // 0..127
    #pragma unroll
    for (int it = 0; it < 2; ++it) {
      int e = cb * 512 + tid + it * 256;   // 0..65535
      int r  = e >> 5;                      // 0..2047
      int m4 = (e & 31) * 4;
      float4 s = *(const float4*)(P + (size_t)r * MOUT + m4);
      #pragma unroll
      for (int k = 1; k < KP; ++k) {
        float4 p = *(const float4*)(P + ((size_t)k * CROWS + r) * MOUT + m4);
        s.x = __fadd_rn(s.x, p.x);
        s.y = __fadd_rn(s.y, p.y);
        s.z = __fadd_rn(s.z, p.z);
        s.w = __fadd_rn(s.w, p.w);
      }
      int gr = cC * CROWS + r;
      int t = gr >> 4, b = gr & 15;
      float4 res;
      res.x = __fdiv_rn(s.x, 16.0f);
      res.y = __fdiv_rn(s.y, 16.0f);
      res.z = __fdiv_rn(s.z, 16.0f);
      res.w = __fdiv_rn(s.w, 16.0f);
      *(float4*)(out + ((size_t)b * TLEN + t) * MOUT + m4) = res;
    }
  }
}

// ---------------------------------------------------------------------------
extern "C" void kernel_launch(void* const* d_in, const int* in_sizes, int n_in,
                              void* d_out, int out_size, void* d_ws, size_t ws_size,
                              hipStream_t stream) {
  const float* x     = (const float*)d_in[0];
  const float* R     = (const float*)d_in[1];
  const float* theta = (const float*)d_in[2];
  const float* C     = (const float*)d_in[3];
  const float* D     = (const float*)d_in[4];
  const float* Do    = (const float*)d_in[5];
  float* out = (float*)d_out;
  float* ws  = (float*)d_ws;
  float*  xcq = ws + XCQ_OFF;
  float2* lam = (float2*)(ws + LAM_OFF);
  float2* Bq  = (float2*)(ws + BQ_OFF);
  float2* Cp  = (float2*)(ws + CP_OFF);
  float*  st  = ws + ST_OFF;
  float2* S2  = (float2*)(ws + S2_OFF);
  float*  P   = ws + P_OFF;

  hipLaunchKernelGGL(k_lam_B, dim3(256),  dim3(256), 0, stream, theta, lam, Bq);
  hipLaunchKernelGGL(k_Cp,    dim3(1024), dim3(128), 0, stream, theta, C, Cp);
  hipLaunchKernelGGL(k_xc,    dim3(1024), dim3(256), 0, stream, x, R, xcq);
  for (int L = 0; L <= NCHUNK + 1; ++L) {
    int nKy   = (L >= 1 && L <= NCHUNK) ? 1024 : 0;
    int nScan = (L < NCHUNK) ? 64 : 0;
    int nComb = (L >= 2) ? 128 : 0;
    hipLaunchKernelGGL(k_fused, dim3(nKy + nScan + nComb), dim3(256), 0, stream,
                       L, lam, Bq, xcq, Cp, D, Do, S2, P, st, out);
  }
}